// Round 11
// baseline (201.782 us; speedup 1.0000x reference)
//
#include <hip/hip_runtime.h>

// 2-layer LSTM (B=4096, T=256, I=38, H1=50, H2=15) + FC on last step.
// R11 = R10 (swapped-operand MFMA, in-register update, SB=16, 512 thr,
// 1 block/CU, one barrier/step) + 8-step double-buffered x window in LDS:
// float4 HBM loads once per 8 steps (drain amortized), per-step x staging
// is LDS->LDS only, so 7 of 8 barriers have no outstanding VMEM to drain.

typedef _Float16 f16x8 __attribute__((ext_vector_type(8)));
typedef _Float16 f16x4 __attribute__((ext_vector_type(4)));
typedef float    f32x4 __attribute__((ext_vector_type(4)));

#if __has_builtin(__builtin_amdgcn_exp2f)
#define DEV_EXP2(x) __builtin_amdgcn_exp2f(x)
#else
#define DEV_EXP2(x) exp2f(x)
#endif
#if __has_builtin(__builtin_amdgcn_rcpf)
#define DEV_RCP(x) __builtin_amdgcn_rcpf(x)
#else
#define DEV_RCP(x) (1.0f/(x))
#endif

#define I1 38
#define H1 50
#define H2 15
#define NC 14
#define TT 256
#define SB 16
// A-row (f16): [x:0..37 | h1:38..87 | h2:88..102 | zero:..127 | pad..135]
#define XS 136
#define NTH 512
#define WROW 304         // window: 8 steps * 38 f16 per seq
#define L2E 2.885390081777927f
#define L1E 1.442695040888963f

#define MF(A,B,C) __builtin_amdgcn_mfma_f32_16x16x32_f16((A),(B),(C),0,0,0)

__device__ __forceinline__ float sigm(float v)  { return DEV_RCP(1.f + DEV_EXP2(-L1E * v)); }
__device__ __forceinline__ float tanh_f(float v){ return 1.f - 2.f * DEV_RCP(1.f + DEV_EXP2(L2E * v)); }

__launch_bounds__(NTH, 1)
__global__ void lstm2_fused(const float* __restrict__ x,
                            const float* __restrict__ w_ih1, const float* __restrict__ w_hh1,
                            const float* __restrict__ b_ih1, const float* __restrict__ b_hh1,
                            const float* __restrict__ w_ih2, const float* __restrict__ w_hh2,
                            const float* __restrict__ b_ih2, const float* __restrict__ b_hh2,
                            const float* __restrict__ w_fc, const float* __restrict__ b_fc,
                            float* __restrict__ out)
{
  __shared__ __align__(16) _Float16 bufA[2][SB][XS];
  __shared__ __align__(16) _Float16 s_win[2][SB][WROW];   // 8-step x windows

  const int tid  = threadIdx.x;
  const int wv   = tid >> 6;          // 0..7
  const int lane = tid & 63;
  const int lm   = lane & 15;         // seq col
  const int lk   = lane >> 4;         // k chunk / local unit
  const int blk  = blockIdx.x;
  const float* xblk = x + (size_t)blk * SB * TT * I1;

  // ---- zero A buffers ----
  for (int i = tid; i < 2*SB*XS; i += NTH) ((_Float16*)bufA)[i] = (_Float16)0.f;

  // ---- weight element fetch (unified-k, gate-row r = 4u+g) ----
  auto welem = [&](bool il1, bool valid, int u, int g, int k) -> _Float16 {
    float w = 0.f;
    if (valid) {
      if (il1) {
        if (k < I1)                w = w_ih1[(g*H1 + u)*I1 + k];
        else if (k < I1 + H1)      w = w_hh1[(g*H1 + u)*H1 + (k - I1)];
      } else {
        if (k >= I1 && k < I1+H1)             w = w_ih2[(g*H2 + u)*H1 + (k - I1)];
        else if (k >= I1+H1 && k < I1+H1+H2)  w = w_hh2[(g*H2 + u)*H2 + (k - I1 - H1)];
      }
    }
    return (_Float16)w;
  };

  // ---- W fragments: row = lm (gate-row within tile), k = ks*32 + lk*8 + e ----
  const int t1 = wv + 8;
  const int r0 = wv*16 + lm, u0f = r0 >> 2, g0 = r0 & 3;     // tile wv: always L1
  const int r1 = t1*16 + lm, q1 = r1 >> 2, g1 = r1 & 3;
  const bool il1f = (q1 < H1);
  const int  u1f = il1f ? q1 : (q1 - H1);
  const bool w16 = (wv == 0);
  const bool c16 = w16 && (lm < 4);          // tile16 valid rows: unit 64, g=lm

  f16x8 W0[3], W1[4], W16[3];
  #pragma unroll
  for (int ks = 0; ks < 3; ++ks) {
    f16x8 v;
    #pragma unroll
    for (int e = 0; e < 8; ++e) v[e] = welem(true, true, u0f, g0, ks*32 + lk*8 + e);
    W0[ks] = v;
  }
  #pragma unroll
  for (int ks = 0; ks < 4; ++ks) {
    f16x8 v;
    #pragma unroll
    for (int e = 0; e < 8; ++e) v[e] = welem(il1f, true, u1f, g1, ks*32 + lk*8 + e);
    W1[ks] = v;
  }
  #pragma unroll
  for (int j = 0; j < 3; ++j) {
    f16x8 v;
    #pragma unroll
    for (int e = 0; e < 8; ++e) v[e] = welem(false, c16, 14, lm & 3, (j+1)*32 + lk*8 + e);
    W16[j] = v;
  }

  // ---- update geometry: lane (lm, lk) owns (unit 4*tile+lk, seq lm) ----
  const int uS0 = 4*wv + lk;                 // slot0: 0..31, always L1
  const int d0  = 38 + uS0;
  const int uS1 = 32 + 4*wv + lk;            // slot1: 32..63
  const bool il1u = (uS1 < H1);
  const int  uS1r = il1u ? uS1 : (uS1 - H1);
  const int  d1   = il1u ? (38 + uS1) : (88 + uS1r);
  const bool hasC = w16 && (lk == 0);        // tile16: unit 64 = L2 u14

  // ---- biases into MFMA C-init ----
  float sb0[4], sb1[4], sbC[4];
  #pragma unroll
  for (int m = 0; m < 4; ++m) {
    sb0[m] = b_ih1[m*H1 + uS0] + b_hh1[m*H1 + uS0];
    sb1[m] = il1u ? (b_ih1[m*H1 + uS1] + b_hh1[m*H1 + uS1])
                  : (b_ih2[m*H2 + uS1r] + b_hh2[m*H2 + uS1r]);
    sbC[m] = b_ih2[m*H2 + 14] + b_hh2[m*H2 + 14];
  }

  // ---- window loader: 16 seqs x 76 float4 -> f16, every 8 steps ----
  auto load_window = [&](int t0, int buf) {
    #pragma unroll
    for (int it = 0; it < 3; ++it) {
      int c = it*NTH + tid;                 // 0..1215
      if (c < SB*76) {
        int s = c / 76, r = c % 76;
        const float4 v = *(const float4*)(xblk + (size_t)s*(TT*I1) + t0*I1 + 4*r);
        f16x4 h;
        h[0] = (_Float16)v.x; h[1] = (_Float16)v.y;
        h[2] = (_Float16)v.z; h[3] = (_Float16)v.w;
        *(f16x4*)&s_win[buf][s][4*r] = h;
      }
    }
  };

  // ---- per-step x copy map: 608 f16 over 512 threads ----
  const int e1x = tid + 512;
  const bool v1 = (tid < SB*I1 - 512);       // tid < 96
  const int s0 = tid / I1,  k0 = tid % I1;
  const int s1 = e1x / I1,  k1 = e1x % I1;
  const int lb0 = s0*XS + k0, lb1 = v1 ? (s1*XS + k1) : 0;

  load_window(0, 0);
  load_window(8, 1);
  __syncthreads();              // zeros + windows visible
  {                             // stage x(0) from window 0
    _Float16* b0 = &bufA[0][0][0];
    b0[lb0] = s_win[0][s0][k0];
    if (v1) b0[lb1] = s_win[0][s1][k1];
  }
  __syncthreads();

  float cS0 = 0.f, cS1 = 0.f, cC = 0.f;

  for (int t = 0; t <= TT; ++t) {
    _Float16* cur = &bufA[t & 1][0][0];
    _Float16* nxt = &bufA[(t & 1) ^ 1][0][0];

    // refill next window once per 8 steps (write buffer last read 1 barrier ago)
    if ((t & 7) == 7 && t + 9 < TT)
      load_window(t + 9, ((t + 9) >> 3) & 1);

    f16x8 a0 = *(const f16x8*)(cur + lm*XS +      lk*8);
    f16x8 a1 = *(const f16x8*)(cur + lm*XS + 32 + lk*8);
    f16x8 a2 = *(const f16x8*)(cur + lm*XS + 64 + lk*8);
    f16x8 a3 = *(const f16x8*)(cur + lm*XS + 96 + lk*8);

    {
      f32x4 acc = (f32x4){sb0[0], sb0[1], sb0[2], sb0[3]};
      acc = MF(W0[0], a0, acc);
      acc = MF(W0[1], a1, acc);
      acc = MF(W0[2], a2, acc);
      if (t < TT) {
        float ig = sigm(acc[0]), fg = sigm(acc[1]);
        float gg = tanh_f(acc[2]), og = sigm(acc[3]);
        cS0 = fg*cS0 + ig*gg;
        nxt[lm*XS + d0] = (_Float16)(og * tanh_f(cS0));
      }
    }
    {
      f32x4 acc = (f32x4){sb1[0], sb1[1], sb1[2], sb1[3]};
      acc = MF(W1[0], a0, acc);
      acc = MF(W1[1], a1, acc);
      acc = MF(W1[2], a2, acc);
      acc = MF(W1[3], a3, acc);
      const bool up = il1u ? (t < TT) : (t >= 1);
      if (up) {
        float ig = sigm(acc[0]), fg = sigm(acc[1]);
        float gg = tanh_f(acc[2]), og = sigm(acc[3]);
        cS1 = fg*cS1 + ig*gg;
        nxt[lm*XS + d1] = (_Float16)(og * tanh_f(cS1));
      }
    }
    if (w16) {
      f32x4 acc = (f32x4){sbC[0], sbC[1], sbC[2], sbC[3]};
      acc = MF(W16[0], a1, acc);
      acc = MF(W16[1], a2, acc);
      acc = MF(W16[2], a3, acc);
      if (hasC && t >= 1) {
        float ig = sigm(acc[0]), fg = sigm(acc[1]);
        float gg = tanh_f(acc[2]), og = sigm(acc[3]);
        cC = fg*cC + ig*gg;
        nxt[lm*XS + 102] = (_Float16)(og * tanh_f(cC));
      }
    }

    // stage x(t+1) from resident window (LDS->LDS, no VMEM)
    if (t + 1 < TT) {
      const int tw = (t + 1) & 7, bw = ((t + 1) >> 3) & 1;
      nxt[lb0] = s_win[bw][s0][tw*I1 + k0];
      if (v1) nxt[lb1] = s_win[bw][s1][tw*I1 + k1];
    }

    __syncthreads();
  }

  // ---- FC on h2(255) (bufA[1], cols 88..102) ----
  if (tid < SB*NC) {
    int s = tid / NC, n = tid % NC;
    float acc = b_fc[n];
    #pragma unroll
    for (int u = 0; u < H2; ++u)
      acc += (float)bufA[1][s][88 + u] * w_fc[n*H2 + u];
    out[((size_t)blk*SB + s)*NC + n] = acc;
  }
}

extern "C" void kernel_launch(void* const* d_in, const int* in_sizes, int n_in,
                              void* d_out, int out_size, void* d_ws, size_t ws_size,
                              hipStream_t stream) {
  (void)n_in; (void)d_ws; (void)ws_size; (void)out_size;
  const float* x     = (const float*)d_in[0];
  const float* w_ih1 = (const float*)d_in[1];
  const float* w_hh1 = (const float*)d_in[2];
  const float* b_ih1 = (const float*)d_in[3];
  const float* b_hh1 = (const float*)d_in[4];
  const float* w_ih2 = (const float*)d_in[5];
  const float* w_hh2 = (const float*)d_in[6];
  const float* b_ih2 = (const float*)d_in[7];
  const float* b_hh2 = (const float*)d_in[8];
  const float* w_fc  = (const float*)d_in[9];
  const float* b_fc  = (const float*)d_in[10];
  float* out = (float*)d_out;

  const int B = in_sizes[0] / (TT * I1);   // 4096
  dim3 grid(B / SB), block(NTH);
  lstm2_fused<<<grid, block, 0, stream>>>(x, w_ih1, w_hh1, b_ih1, b_hh1,
                                          w_ih2, w_hh2, b_ih2, b_hh2,
                                          w_fc, b_fc, out);
}